// Round 7
// baseline (288.011 us; speedup 1.0000x reference)
//
#include <hip/hip_runtime.h>

// Problem constants (static shapes from reference)
#define B 64
#define C 2048
#define H 24
#define W 8
#define HW (H * W)            // 192 spatial positions per (b,c)
#define HW4 (HW / 4)          // 48 float4 per channel row
#define CHUNKS 16             // channel chunks per batch
#define CPC (C / CHUNKS)      // 128 channels per chunk
#define RH 8                  // round(0.33 * 24) = 8 rows zeroed
#define CHW4 ((C * HW) / 4)   // float4s per batch = 98304
#define GRID (B * CHUNKS)     // 1024 blocks: one (b,chunk) each
#define TPB 192               // 3 waves

typedef float f32x4 __attribute__((ext_vector_type(4)));

// ---------------------------------------------------------------------------
// Init: zero the per-batch arrival counters (ws is poisoned every iteration;
// this launch is in the captured graph so it replays each time).
// ---------------------------------------------------------------------------
__global__ __launch_bounds__(64) void k_init(unsigned int* __restrict__ counters) {
    if (threadIdx.x < B) counters[threadIdx.x] = 0u;
}

// ---------------------------------------------------------------------------
// Single-pass kernel, Round-6 structure with ONE change: the semaphore spin
// polls with RELAXED atomic loads and issues a single acquire fence after
// the loop. Round 6 (acquire per poll) emitted a buffer_inv cache-invalidate
// on EVERY poll x 1024 waves -> device-wide L1/L2 thrash -> phase-1 stream
// collapsed to 1.34 TB/s and k_one took 153 us despite floor-perfect traffic
// (FETCH 101.5 MB / WRITE 99 MB). Relaxed polls still observe the counter
// (atomics read the coherent point); visibility of partials is established
// once by the post-loop fence (release-fence/acquire-fence pairing - the
// same guarantee that already measured absmax 0).
// ---------------------------------------------------------------------------
__global__ __launch_bounds__(TPB) void k_one(const f32x4* __restrict__ x4,
                                             f32x4* __restrict__ partial4,
                                             unsigned int* __restrict__ counters,
                                             f32x4* __restrict__ out4) {
    const int blk = blockIdx.x;
    const int b = blk / CHUNKS;
    const int chunk = blk % CHUNKS;
    const int t = threadIdx.x;
    const int q = t % HW4;   // float4 spatial position (fixed per thread)
    const int g = t / HW4;   // channel subgroup (0..3)

    const size_t xoff = (size_t)(b * C + chunk * CPC + g) * HW4 + q;
    const f32x4* p = x4 + xoff;

    // ---- Phase 1: sum of squares (verbatim verified k_ss) ----
    f32x4 acc = {0.f, 0.f, 0.f, 0.f};
    #pragma unroll
    for (int j = 0; j < CPC / 4; ++j) {          // 32 iters, 16 B/lane coalesced
        const f32x4 v = p[(size_t)j * 4 * HW4];
        acc += v * v;
    }
    __shared__ f32x4 sm[4][HW4];  // 3 KB
    __shared__ float smask[H];
    sm[g][q] = acc;
    __syncthreads();
    if (t < HW4)
        partial4[(size_t)blk * HW4 + t] =
            (sm[0][t] + sm[1][t]) + (sm[2][t] + sm[3][t]);
    __syncthreads();  // partial stores complete before the release fence

    // ---- Per-batch semaphore: release add, RELAXED spin, one acquire ----
    if (t == 0) {
        __threadfence();              // release: flush partials device-wide
        atomicAdd(&counters[b], 1u);  // device-scope RMW
        unsigned int spins = 0;
        while (__hip_atomic_load(&counters[b], __ATOMIC_RELAXED,
                                 __HIP_MEMORY_SCOPE_AGENT) < CHUNKS) {
            __builtin_amdgcn_s_sleep(2);
            if (++spins > 1000000u) break;  // bounded: sync failure -> wrong
                                            // answer (diagnosable), not hang
        }
        __threadfence();  // acquire: invalidate stale lines ONCE, not per poll
    }
    __syncthreads();

    // ---- Phase 2: rank rows (verbatim verified k_mask math; wave 0) ----
    if (t < 64) {
        f32x4 s = {0.f, 0.f, 0.f, 0.f};
        if (t < HW4) {
            #pragma unroll
            for (int ch = 0; ch < CHUNKS; ++ch)  // fixed order: deterministic
                s += partial4[(size_t)(b * CHUNKS + ch) * HW4 + t];
        }
        float m = fmaxf(fmaxf(s.x, s.y), fmaxf(s.z, s.w));
        m = fmaxf(m, __shfl_xor(m, 1));  // row h max now at lane 2h
        const float my = __shfl(m, 2 * (t < H ? t : 0));
        int cnt = 0;
        #pragma unroll
        for (int h = 0; h < H; ++h) {
            const float o = __shfl(m, 2 * h);
            if (o > my || (o == my && h > t)) ++cnt;  // stable-argsort tie-break
        }
        if (t < H) smask[t] = (cnt < RH) ? 0.0f : 1.0f;
    }
    __syncthreads();

    // ---- Phase 3: apply. h = q/2 is CONSTANT per thread. ----
    const float m = smask[q >> 1];
    f32x4* o = out4 + xoff;
    #pragma unroll
    for (int j = 0; j < CPC / 4; ++j) {
        const f32x4 v = p[(size_t)j * 4 * HW4];  // L3-warm re-read
        __builtin_nontemporal_store(v * m, o + (size_t)j * 4 * HW4);
    }
}

// ---------------------------------------------------------------------------
extern "C" void kernel_launch(void* const* d_in, const int* in_sizes, int n_in,
                              void* d_out, int out_size, void* d_ws, size_t ws_size,
                              hipStream_t stream) {
    const f32x4* x4 = (const f32x4*)d_in[0];
    f32x4* out4 = (f32x4*)d_out;
    f32x4* partial4 = (f32x4*)d_ws;  // B*CHUNKS*HW floats (768 KB)
    unsigned int* counters =
        (unsigned int*)((float*)d_ws + (size_t)B * CHUNKS * HW);  // 64 uints

    k_init<<<1, 64, 0, stream>>>(counters);
    k_one<<<GRID, TPB, 0, stream>>>(x4, partial4, counters, out4);
}

// Round 8
// 206.890 us; speedup vs baseline: 1.3921x; 1.3921x over previous
//
#include <hip/hip_runtime.h>

// Problem constants (static shapes from reference)
#define B 64
#define C 2048
#define H 24
#define W 8
#define HW (H * W)            // 192 spatial positions per (b,c)
#define HW4 (HW / 4)          // 48 float4 per channel row
#define CHUNKS 16             // channel chunks per batch
#define CPC (C / CHUNKS)      // 128 channels per chunk
#define RH 8                  // round(0.33 * 24) = 8 rows dropped
#define CHW4 ((C * HW) / 4)   // float4s per batch = 98304
#define TPB 192               // 3 waves (k1)
#define ZBLKS 32              // zero-blocks per batch (k2)
#define ZTPB 256              // k2 block size
// per batch: RH*C*(W*2/8) = 8*2048*2 = 32768 zero-float4s
// per k2 block: 32768/32 = 1024; per thread: 1024/256 = 4

typedef float f32x4 __attribute__((ext_vector_type(4)));

// ---------------------------------------------------------------------------
// Kernel 1: sumsq partials (verbatim verified k_ss) + NT copy out = x in the
// same pass. Kept rows of out are final after this kernel (x*1.0 == x
// bitwise); dropped rows get overwritten by k2. One balanced read+write
// stream: 100.7 MB in + 100.7 MB out ≈ 33 µs at ~6 TB/s.
// ---------------------------------------------------------------------------
__global__ __launch_bounds__(TPB) void k_ss_copy(const f32x4* __restrict__ x4,
                                                 f32x4* __restrict__ partial4,
                                                 f32x4* __restrict__ out4) {
    const int blk = blockIdx.x;
    const int b = blk / CHUNKS;
    const int chunk = blk % CHUNKS;
    const int t = threadIdx.x;
    const int q = t % HW4;   // float4 spatial position
    const int g = t / HW4;   // channel subgroup (0..3)

    const size_t xoff = (size_t)(b * C + chunk * CPC + g) * HW4 + q;
    const f32x4* p = x4 + xoff;
    f32x4* o = out4 + xoff;

    f32x4 acc = {0.f, 0.f, 0.f, 0.f};
    #pragma unroll
    for (int j = 0; j < CPC / 4; ++j) {          // 32 iters, 16 B/lane coalesced
        const f32x4 v = p[(size_t)j * 4 * HW4];
        acc += v * v;
        __builtin_nontemporal_store(v, o + (size_t)j * 4 * HW4);  // out = x
    }
    __shared__ f32x4 sm[4][HW4];  // 3 KB
    sm[g][q] = acc;
    __syncthreads();
    if (t < HW4)
        partial4[(size_t)blk * HW4 + t] =          // regular store: L2-hot for k2
            (sm[0][t] + sm[1][t]) + (sm[2][t] + sm[3][t]);
}

// ---------------------------------------------------------------------------
// Kernel 2: rank rows (verbatim verified math, redundantly per block from the
// batch's 12 KB of partials), ballot-compact the RH dropped rows, zero-fill
// this block's slice of them. Writes only B*C*RH*W*4 = 33.5 MB — replaces
// the old 100 MB L3 re-read + 100 MB re-write apply pass.
// Dropped rows: 0.0f vs reference x*0.0 = ±0.0 -> |diff| = 0. x finite.
// grid = B*ZBLKS, block = 256. No cross-block sync anywhere.
// ---------------------------------------------------------------------------
__global__ __launch_bounds__(ZTPB) void k_mask_zero(const f32x4* __restrict__ partial4,
                                                    f32x4* __restrict__ out4) {
    const int b = blockIdx.x / ZBLKS;
    const int s = blockIdx.x % ZBLKS;
    const int t = threadIdx.x;
    __shared__ int drp[RH];

    // ---- Rank rows (wave 0; verbatim verified shuffle math) ----
    if (t < 64) {
        f32x4 sum = {0.f, 0.f, 0.f, 0.f};
        if (t < HW4) {
            #pragma unroll
            for (int ch = 0; ch < CHUNKS; ++ch)  // fixed order: deterministic
                sum += partial4[(size_t)(b * CHUNKS + ch) * HW4 + t];
        }
        float m = fmaxf(fmaxf(sum.x, sum.y), fmaxf(sum.z, sum.w));
        m = fmaxf(m, __shfl_xor(m, 1));  // row h max now at lane 2h
        const float my = __shfl(m, 2 * (t < H ? t : 0));
        int cnt = 0;
        #pragma unroll
        for (int h = 0; h < H; ++h) {
            const float o = __shfl(m, 2 * h);
            if (o > my || (o == my && h > t)) ++cnt;  // stable-argsort tie-break
        }
        // cnt is a permutation of 0..H-1 over t<H; dropped rows: cnt < RH.
        const bool pred = (t < H) && (cnt < RH);
        const unsigned long long ball = __ballot(pred);  // 64-bit wave mask
        if (pred) {
            const int rank = __popcll(ball & ((1ull << t) - 1ull));
            drp[rank] = t;  // exactly RH entries
        }
    }
    __syncthreads();

    // ---- Zero this block's slice of the dropped rows ----
    // j in [0, 32768) per batch: c = j>>4, k = (j&15)>>1, w4 = j&1.
    // Consecutive threads (w4 pair) write 32 B contiguous.
    const size_t ob = (size_t)b * CHW4;
    const f32x4 z = {0.f, 0.f, 0.f, 0.f};
    #pragma unroll
    for (int r = 0; r < 4; ++r) {
        const int j = s * (ZTPB * 4) + r * ZTPB + t;
        const int c = j >> 4;
        const int k = (j & 15) >> 1;
        const int w4 = j & 1;
        const size_t e = ob + (size_t)c * HW4 + (size_t)drp[k] * 2 + w4;
        __builtin_nontemporal_store(z, (f32x4*)(out4 + e));
    }
}

// ---------------------------------------------------------------------------
extern "C" void kernel_launch(void* const* d_in, const int* in_sizes, int n_in,
                              void* d_out, int out_size, void* d_ws, size_t ws_size,
                              hipStream_t stream) {
    const f32x4* x4 = (const f32x4*)d_in[0];
    f32x4* out4 = (f32x4*)d_out;
    f32x4* partial4 = (f32x4*)d_ws;  // B*CHUNKS*HW floats (768 KB)

    k_ss_copy<<<B * CHUNKS, TPB, 0, stream>>>(x4, partial4, out4);
    k_mask_zero<<<B * ZBLKS, ZTPB, 0, stream>>>(partial4, out4);
}